// Round 6
// baseline (39.118 us; speedup 1.0000x reference)
//
#include <hip/hip_runtime.h>

// Problem constants: B=8192, NJ=14, COL=14, sigma=1, radius=4.
#define NJ    14
#define TILE  196            // floats per tile (= 49 float4, 784 B)
#define BLK   256
#define JPB   64             // joints per block; 16 per wave
#define TPW   16             // tiles per wave
#define REG4  (TPW * 49)     // 784 float4 per wave region (12544 B)

typedef __attribute__((address_space(1))) const void g_void;
typedef __attribute__((address_space(3))) void lds_void;

// exp(-0.5*d*d) with the 9-tap cutoff (|d|<=4), via v_exp_f32.
__device__ __forceinline__ float gtap(int d) {
  const int d2 = d * d;
  const float e = exp2f(-0.72134752044448169f * (float)d2);  // 0.5*log2(e)
  return (d2 <= 16) ? e : 0.0f;
}

// 1-D blurred-impulse response at position p for peak pk, with scipy
// 'reflect' padding folded in. Unnormalized (kernel-sum cancels in g/max).
__device__ __forceinline__ float uresp(int p, int pk) {
  float s = gtap(p - pk);
  if (p <= 3)  s += gtap(p + pk + 1);   // low reflection  (q<0 -> -1-q)
  if (p >= 10) s += gtap(27 - p - pk);  // high reflection (q>13 -> 27-q)
  return s;
}

__device__ __forceinline__ float wave_sum(float x) {
#pragma unroll
  for (int off = 32; off >= 1; off >>= 1) x += __shfl_xor(x, off);
  return x;
}

// Quarter Q of one tile: float4 indices f = 4i + Q. Compile-time element
// indices -> uy/ux stay in registers (rule #20).
template<int Q>
__device__ __forceinline__ void accum_part(const float4* __restrict__ hp,
    const float (&uy)[14], const float (&ux)[14],
    float& bm, int& bi, float& sh2, float& cross, float& q0)
{
  const int NI = (Q == 0) ? 13 : 12;   // 49 float4 = 13+12+12+12
#pragma unroll
  for (int i = 0; i < NI; ++i) {
    const int f = 4 * i + Q;
    const float4 q = hp[f];            // ds_read_b128
    const float qa[4] = {q.x, q.y, q.z, q.w};
#pragma unroll
    for (int c = 0; c < 4; ++c) {
      const int idx = 4 * f + c;
      const int y = idx / 14;
      const int x = idx - 14 * y;            // compile-time
      const float hv = qa[c];
      if (hv > bm) { bm = hv; bi = idx; }    // first-index within quarter
      sh2 = fmaf(hv, hv, sh2);
      if (y == 0) q0 = fmaf(hv, hv, q0);     // row-0 energy (invis fixup)
      cross = fmaf(hv, uy[y] * ux[x], cross);
    }
  }
}

__global__ __launch_bounds__(BLK, 3) void joint_kernel(
    const float* __restrict__ o, const float* __restrict__ h,
    const float* __restrict__ t, const float* __restrict__ v,
    float* __restrict__ part, int njoint, int nblocks)
{
  __shared__ __align__(16) float lds[4 * REG4 * 4];  // 50176 B, 4 wave regions
  __shared__ float rs[4], rn[4];

  const int tid  = threadIdx.x;
  const int lane = tid & 63;
  const int wid  = tid >> 6;
  const int tl   = lane >> 2;          // local tile 0..15 within wave region
  const int qq   = lane & 3;           // quarter 0..3 of that tile
  const int jg   = blockIdx.x * JPB + wid * TPW + tl;   // this lane's joint
  const bool valid = jg < njoint;      // njoint = 1792*64 exactly; kept for safety

  // ---- per-wave coalesced stage of its OWN 16 tiles (no cross-wave dep) ----
  {
    const float* gsrc = h + ((size_t)blockIdx.x * JPB + wid * TPW) * TILE;
    float* ldst = lds + (size_t)wid * REG4 * 4;
#pragma unroll
    for (int i = 0; i < 13; ++i) {
      const int f4 = i * 64 + lane;          // f4 index within region
      if (f4 < REG4) {
        __builtin_amdgcn_global_load_lds(
            (g_void*)(gsrc + (size_t)f4 * 4),
            (lds_void*)(ldst + (size_t)f4 * 4),   // uniform base + lane*16
            16, 0, 0);
      }
    }
  }

  // ---- overlap: analytic 1-D responses while this wave's loads fly ----
  float uy[14], ux[14];
  float2 tv = make_float2(0.0f, 0.0f);
  int xi = 0, yi = 0;
  if (valid) {
    tv = ((const float2*)t)[jg];
    xi = min(max((int)(tv.x * 14.0f), 0), 13);
    yi = min(max((int)(tv.y * 14.0f), 0), 13);
#pragma unroll
    for (int p = 0; p < 14; ++p) { uy[p] = uresp(p, yi); ux[p] = uresp(p, xi); }
  }

  // per-wave drain of this wave's 13 loads; NO block barrier
  asm volatile("s_waitcnt vmcnt(0)" ::: "memory");

  // ---- quarter pass over this lane's tile (4-way divergent, 16 lanes ea) ----
  float bm = -3.0e38f; int bi = 0;
  float sh2 = 0.0f, cross = 0.0f, q0 = 0.0f;
  if (valid) {
    const float4* hp = (const float4*)(lds + ((size_t)wid * REG4 + tl * 49) * 4);
    switch (qq) {
      case 0: accum_part<0>(hp, uy, ux, bm, bi, sh2, cross, q0); break;
      case 1: accum_part<1>(hp, uy, ux, bm, bi, sh2, cross, q0); break;
      case 2: accum_part<2>(hp, uy, ux, bm, bi, sh2, cross, q0); break;
      default: accum_part<3>(hp, uy, ux, bm, bi, sh2, cross, q0); break;
    }
  }

  // ---- combine the 4 quarters via intra-group shuffles (no LDS, no barrier) ----
#pragma unroll
  for (int off = 1; off <= 2; off <<= 1) {
    const float om = __shfl_xor(bm, off);
    const int   oi = __shfl_xor(bi, off);
    if (om > bm || (om == bm && oi < bi)) { bm = om; bi = oi; }  // first-index
    sh2   += __shfl_xor(sh2, off);
    cross += __shfl_xor(cross, off);
    q0    += __shfl_xor(q0, off);
  }

  // ---- epilogue on quarter-0 lanes (16 per wave, all waves concurrent) ----
  float s_acc = 0.0f, n_acc = 0.0f;
  if (valid && qq == 0) {
    const float2 vv = ((const float2*)v)[jg];
    const bool vis = ((int)vv.x) == 1;

    float Sy2 = 0.0f, Sx2 = 0.0f;
#pragma unroll
    for (int p = 0; p < 14; ++p) {
      Sy2 = fmaf(uy[p], uy[p], Sy2);
      Sx2 = fmaf(ux[p], ux[p], Sx2);
    }
    const float maxy = 1.0f + gtap(2 * yi + 1) + gtap(27 - 2 * yi);
    const float maxx = 1.0f + gtap(2 * xi + 1) + gtap(27 - 2 * xi);
    const float inv = vis ? (1.0f / (maxy * maxx)) : 0.0f;

    // sum(h-tt)^2 = sh2 - 2*inv*cross + inv^2*Sy2*Sx2 ; row0 zeroed if invis
    float s = sh2 - 2.0f * inv * cross + inv * inv * Sy2 * Sx2;
    if (!vis) s -= q0;

    // ---- coordinate loss (argmax-dependent gather, stays global) ----
    const int b = jg / NJ;
    const int j = jg - b * NJ;
    const int yC = bi / 14;
    const int xC = bi - 14 * yC;
    const size_t ob = ((size_t)b * (2 * NJ) + j) * TILE + (size_t)bi;
    const float ox = o[ob];
    const float oy = o[ob + (size_t)NJ * TILE];
    const bool cond = bm > 0.5f;
    const float sc = 1.0f / 14.0f;
    const float px = cond ? (ox + (float)xC) * sc : 0.0f;
    const float py = cond ? (oy + (float)yC) * sc : 0.0f;
    const float d0 = (px - tv.x) * vv.x;
    const float d1 = (py - tv.y) * vv.y;
    s += d0 * d0 + d1 * d1;

    s_acc = s;
    n_acc = vv.x + vv.y;
  }

  // ---- per-wave deterministic sum; single end-of-kernel barrier ----
  s_acc = wave_sum(s_acc);
  n_acc = wave_sum(n_acc);
  if (lane == 0) { rs[wid] = s_acc; rn[wid] = n_acc; }
  __syncthreads();
  if (tid == 0) {
    part[blockIdx.x]           = rs[0] + rs[1] + rs[2] + rs[3];
    part[nblocks + blockIdx.x] = rn[0] + rn[1] + rn[2] + rn[3];
  }
}

__global__ __launch_bounds__(BLK) void finalize_kernel(
    const float* __restrict__ part, float* __restrict__ out, int nblocks)
{
  float s = 0.0f, n = 0.0f;
  for (int i = threadIdx.x; i < nblocks; i += BLK) {
    s += part[i];
    n += part[nblocks + i];
  }
  s = wave_sum(s);
  n = wave_sum(n);
  __shared__ float rs[4], rn[4];
  const int lane = threadIdx.x & 63, wid = threadIdx.x >> 6;
  if (lane == 0) { rs[wid] = s; rn[wid] = n; }
  __syncthreads();
  if (threadIdx.x == 0) {
    const float S = rs[0] + rs[1] + rs[2] + rs[3];
    const float N = rn[0] + rn[1] + rn[2] + rn[3];
    out[0] = S / (0.5f * N);   // (d1_sum + d2_sum) / N1, N1 = sum(v)/2
  }
}

extern "C" void kernel_launch(void* const* d_in, const int* in_sizes, int n_in,
                              void* d_out, int out_size, void* d_ws, size_t ws_size,
                              hipStream_t stream)
{
  const float* o = (const float*)d_in[0];  // [B, 2*NJ, 14, 14]
  const float* h = (const float*)d_in[1];  // [B, NJ, 14, 14]
  const float* t = (const float*)d_in[2];  // [B, NJ, 2]
  const float* v = (const float*)d_in[3];  // [B, NJ, 2]
  const int njoint = in_sizes[1] / TILE;          // B*NJ = 114688
  const int nblocks = (njoint + JPB - 1) / JPB;   // 1792

  float* part = (float*)d_ws;  // 2*nblocks floats, fully rewritten each call
  joint_kernel<<<nblocks, BLK, 0, stream>>>(o, h, t, v, part, njoint, nblocks);
  finalize_kernel<<<1, BLK, 0, stream>>>(part, (float*)d_out, nblocks);
}